// Round 1
// 90.853 us; speedup vs baseline: 1.0386x; 1.0386x over previous
//
#include <hip/hip_runtime.h>
#include <math.h>

#define BB 16
#define TT 2048
#define DD 256
#define KK 8
#define TILE 16      // tokens per quad-tile (phase1: 4/wave, phase2: all 16)
#define QUADS 4      // 4 quads of 4 waves = 1024 threads/block
static constexpr float LN_EPS = 1e-5f;

// DPP lane exchange (VALU pipe). 0xB1=quad_perm xor1, 0x4E=quad_perm xor2,
// 0x108=row_shl:8, 0x118=row_shr:8 (16-lane rows, zero-fill).
template<int CTRL>
__device__ __forceinline__ float dppf(float x) {
    return __int_as_float(__builtin_amdgcn_update_dpp(
        0, __float_as_int(x), CTRL, 0xF, 0xF, true));
}

__device__ __forceinline__ void f4add(float4& a, const float4 b) {
    a.x += b.x; a.y += b.y; a.z += b.z; a.w += b.w;
}

// ---------------------------------------------------------------------------
// Fused kernel, v3: same per-wave math as the verified v2, but 1024-thread
// blocks = 4 independent "quads" (each quad == one old 256-thread block).
// Quads tree-merge accumulators in LDS before ONE workspace store, cutting
// the intermediate from C=64 (16.8 MB) to C=16 (4.2 MB). Occupancy per CU
// unchanged: 1 block/CU x 16 waves (was 4 blocks x 4 waves).
// ---------------------------------------------------------------------------
__global__ __launch_bounds__(1024, 4) void lde_fused3(
    const float* __restrict__ x,
    const float* __restrict__ centers,
    const float* __restrict__ scale,
    const float* __restrict__ temperature,
    float* __restrict__ ws_wx,   // [BB*C][KK*512] (0..255 wx | 256..511 wx2)
    float* __restrict__ ws_w,    // [BB*C][KK]
    int C, int NT)               // NT = tiles per quad = (TT/C)/TILE/QUADS
{
    const int c    = blockIdx.x;
    const int b    = blockIdx.y;
    const int tid  = threadIdx.x;
    const int quad = tid >> 8;        // 0..3
    const int r    = tid & 255;       // (wave-in-quad, lane)
    const int wave = (tid >> 6) & 3;  // wave within quad
    const int lane = tid & 63;

    __shared__ float  wbuf[QUADS][TILE * KK];  // 2 KB: per-quad tile weights
    __shared__ float4 mbuf[4][2][256];         // 32 KB: merge buffer (conflict-free layout)
    __shared__ float2 mw[2][256];              // 4 KB: aw merge

    // Per-lane center fragments with -2*temp*scale folded in.
    const float4* cv = reinterpret_cast<const float4*>(centers);
    const float temp = temperature[0];
    float4 c4s[KK]; float A[KK], Bc[KK];
    #pragma unroll
    for (int k = 0; k < KK; ++k) {
        const float4 cc = cv[k * 64 + lane];
        const float a = temp * scale[k];
        A[k]  = a;
        Bc[k] = a * (cc.x*cc.x + cc.y*cc.y + cc.z*cc.z + cc.w*cc.w);
        const float na = -2.0f * a;
        c4s[k] = make_float4(na*cc.x, na*cc.y, na*cc.z, na*cc.w);
    }

    const int bit0 = lane & 1;
    const int bit1 = (lane >> 1) & 1;
    const int bit4 = (lane >> 4) & 1;
    const int v    = (bit0 << 2) | (bit1 << 1) | bit4;  // lane's cluster after reduce
    const bool writer = ((lane & 44) == 0);  // lanes 0-3,16-19: v covers 0..7 once

    // Phase-2 accumulators: clusters kA=2*wave, kB=2*wave+1. 18 regs.
    float4 axA = {0,0,0,0}, ax2A = {0,0,0,0};
    float4 axB = {0,0,0,0}, ax2B = {0,0,0,0};
    float  aw0 = 0.0f, aw1 = 0.0f;

    const int TC = NT * TILE * QUADS;            // tokens per block
    const float4* xr = reinterpret_cast<const float4*>(x + (size_t)b * TT * DD);

    for (int it = 0; it < NT; ++it) {
        const int tile = quad + QUADS * it;      // quad owns tiles quad, quad+4, ...
        const int tb = c * TC + tile * TILE;     // batch-local token base

        // ---------------- Phase 1: weights for this quad's tile (wave-per-token)
        #pragma unroll
        for (int j = 0; j < TILE / 4; ++j) {
            const int tloc = wave * (TILE / 4) + j;
            const float4 cx = xr[(size_t)(tb + tloc) * 64 + lane];

            const float x2p = fmaf(cx.x,cx.x, fmaf(cx.y,cx.y,
                              fmaf(cx.z,cx.z, cx.w*cx.w)));
            float q[KK];
            #pragma unroll
            for (int k = 0; k < KK; ++k) {
                const float rp = fmaf(cx.x,c4s[k].x, fmaf(cx.y,c4s[k].y,
                                 fmaf(cx.z,c4s[k].z, cx.w*c4s[k].w)));
                q[k] = rp + fmaf(A[k], x2p, Bc[k]);
            }

            // halving reduce over lane bits 0 (qp xor1), 1 (qp xor2), 4 (shfl16)
            float a0, a1, a2, a3;
            {
                const float s_0 = bit0 ? q[0] : q[4];
                const float s_1 = bit0 ? q[1] : q[5];
                const float s_2 = bit0 ? q[2] : q[6];
                const float s_3 = bit0 ? q[3] : q[7];
                const float k_0 = bit0 ? q[4] : q[0];
                const float k_1 = bit0 ? q[5] : q[1];
                const float k_2 = bit0 ? q[6] : q[2];
                const float k_3 = bit0 ? q[7] : q[3];
                a0 = k_0 + dppf<0xB1>(s_0);
                a1 = k_1 + dppf<0xB1>(s_1);
                a2 = k_2 + dppf<0xB1>(s_2);
                a3 = k_3 + dppf<0xB1>(s_3);
            }
            float b0, b1;
            {
                const float s_0 = bit1 ? a0 : a2;
                const float s_1 = bit1 ? a1 : a3;
                const float k_0 = bit1 ? a2 : a0;
                const float k_1 = bit1 ? a3 : a1;
                b0 = k_0 + dppf<0x4E>(s_0);
                b1 = k_1 + dppf<0x4E>(s_1);
            }
            float S;
            {
                const float s_ = bit4 ? b0 : b1;
                const float k_ = bit4 ? b1 : b0;
                S = k_ + __shfl_xor(s_, 16, 64);
            }
            // broadcast-reduce lane bits 2, 3, 5 -> S = full total for cluster v
            S += __shfl_xor(S, 4, 64);
            S += dppf<0x108>(S) + dppf<0x118>(S);
            S += __shfl_xor(S, 32, 64);

            // own-cluster softmax weight: min/sum butterflies over v-groups
            float mn = S;
            mn = fminf(mn, dppf<0xB1>(mn));
            mn = fminf(mn, dppf<0x4E>(mn));
            mn = fminf(mn, __shfl_xor(mn, 16, 64));
            const float e = __expf(mn - S);
            float den = e;
            den += dppf<0xB1>(den);
            den += dppf<0x4E>(den);
            den += __shfl_xor(den, 16, 64);
            const float wn = e / den;

            if (writer) wbuf[quad][tloc * KK + v] = wn;
        }
        __syncthreads();

        // ---------------- Phase 2: accumulate 2 clusters/wave over quad's tile
        #pragma unroll 4
        for (int t = 0; t < TILE; ++t) {
            const float4 cx = xr[(size_t)(tb + t) * 64 + lane];   // L1/L2-hot
            const float2 wk = *reinterpret_cast<const float2*>(
                                  &wbuf[quad][t * KK + 2 * wave]); // LDS broadcast
            aw0 += wk.x;  aw1 += wk.y;
            const float xx0 = cx.x*cx.x, xx1 = cx.y*cx.y;
            const float xx2 = cx.z*cx.z, xx3 = cx.w*cx.w;
            axA.x  = fmaf(wk.x, cx.x, axA.x);   axA.y  = fmaf(wk.x, cx.y, axA.y);
            axA.z  = fmaf(wk.x, cx.z, axA.z);   axA.w  = fmaf(wk.x, cx.w, axA.w);
            ax2A.x = fmaf(wk.x, xx0, ax2A.x);   ax2A.y = fmaf(wk.x, xx1, ax2A.y);
            ax2A.z = fmaf(wk.x, xx2, ax2A.z);   ax2A.w = fmaf(wk.x, xx3, ax2A.w);
            axB.x  = fmaf(wk.y, cx.x, axB.x);   axB.y  = fmaf(wk.y, cx.y, axB.y);
            axB.z  = fmaf(wk.y, cx.z, axB.z);   axB.w  = fmaf(wk.y, cx.w, axB.w);
            ax2B.x = fmaf(wk.y, xx0, ax2B.x);   ax2B.y = fmaf(wk.y, xx1, ax2B.y);
            ax2B.z = fmaf(wk.y, xx2, ax2B.z);   ax2B.w = fmaf(wk.y, xx3, ax2B.w);
        }
        __syncthreads();   // before next tile overwrites wbuf
    }

    // ---------------- Cross-quad tree merge (threads with equal r hold the
    // same (cluster, dims) partials), then ONE store for the whole block.
    if (quad >= 2) {
        const int qi = quad - 2;
        mbuf[0][qi][r] = axA;  mbuf[1][qi][r] = ax2A;
        mbuf[2][qi][r] = axB;  mbuf[3][qi][r] = ax2B;
        mw[qi][r] = make_float2(aw0, aw1);
    }
    __syncthreads();
    if (quad < 2) {
        f4add(axA, mbuf[0][quad][r]);  f4add(ax2A, mbuf[1][quad][r]);
        f4add(axB, mbuf[2][quad][r]);  f4add(ax2B, mbuf[3][quad][r]);
        aw0 += mw[quad][r].x;  aw1 += mw[quad][r].y;
    }
    __syncthreads();
    if (quad == 1) {
        mbuf[0][0][r] = axA;  mbuf[1][0][r] = ax2A;
        mbuf[2][0][r] = axB;  mbuf[3][0][r] = ax2B;
        mw[0][r] = make_float2(aw0, aw1);
    }
    __syncthreads();
    if (quad == 0) {
        f4add(axA, mbuf[0][0][r]);  f4add(ax2A, mbuf[1][0][r]);
        f4add(axB, mbuf[2][0][r]);  f4add(ax2B, mbuf[3][0][r]);
        aw0 += mw[0][r].x;  aw1 += mw[0][r].y;

        const size_t base = (size_t)(b * C + c) * (KK * 512);
        const int kA = 2 * wave, kB = 2 * wave + 1;
        *reinterpret_cast<float4*>(ws_wx + base + kA*512       + 4*lane) = axA;
        *reinterpret_cast<float4*>(ws_wx + base + kA*512 + 256 + 4*lane) = ax2A;
        *reinterpret_cast<float4*>(ws_wx + base + kB*512       + 4*lane) = axB;
        *reinterpret_cast<float4*>(ws_wx + base + kB*512 + 256 + 4*lane) = ax2B;
        if (lane == 0) {
            ws_w[(size_t)(b * C + c) * KK + kA] = aw0;
            ws_w[(size_t)(b * C + c) * KK + kB] = aw1;
        }
    }
}

// ---------------------------------------------------------------------------
// Final: per (b,k). 1024 threads, 8 chunk-octets sum in parallel, then
// mean/var (reference decomposition) + layernorm over 512, write out.
// (Unchanged; parameterized by C — now reads 4.2 MB instead of 16.8 MB.)
// ---------------------------------------------------------------------------
__global__ __launch_bounds__(1024) void lde_final4(
    const float* __restrict__ ws_wx,
    const float* __restrict__ ws_w,
    const float* __restrict__ centers,
    float* __restrict__ out,
    int C)
{
    const int b   = blockIdx.x >> 3;
    const int k   = blockIdx.x & 7;
    const int tid = threadIdx.x;
    const int oct = tid >> 7;
    const int j   = tid & 127;

    const float4* base = reinterpret_cast<const float4*>(ws_wx);
    float ax = 0.f, ay = 0.f, az = 0.f, aw = 0.f;
    for (int ci = oct; ci < C; ci += 8) {
        const float4 vv = base[((size_t)((b * C + ci) * KK + k)) * 128 + j];
        ax += vv.x; ay += vv.y; az += vv.z; aw += vv.w;
    }

    __shared__ float4 part[1024];
    __shared__ float  sum[512];
    __shared__ float  swbuf[64];
    part[tid] = make_float4(ax, ay, az, aw);
    if (tid >= 512 && tid < 512 + C)
        swbuf[tid - 512] = ws_w[(size_t)(b * C + (tid - 512)) * KK + k];
    __syncthreads();

    if (tid < 128) {
        float4 t = part[tid];
        #pragma unroll
        for (int o = 1; o < 8; ++o) {
            const float4 u = part[o * 128 + tid];
            t.x += u.x; t.y += u.y; t.z += u.z; t.w += u.w;
        }
        reinterpret_cast<float4*>(sum)[tid] = t;
    }
    __syncthreads();

    if (tid < 256) {
        float sw = 0.0f;
        for (int ci = 0; ci < C; ++ci) sw += swbuf[ci];
        const int d = tid;
        const float wx   = sum[d];
        const float wx2  = sum[256 + d];
        const float ck   = centers[k * DD + d];
        const float mean = wx - ck * sw;
        const float E    = wx2 - 2.0f * ck * wx + ck * ck * sw;
        const float var  = E - mean * mean;
        sum[d]       = mean;
        sum[256 + d] = var;
    }
    __syncthreads();

    float val = (tid < 512) ? sum[tid] : 0.0f;
    float s1 = val, s2 = val * val;
    #pragma unroll
    for (int off = 32; off >= 1; off >>= 1) {
        s1 += __shfl_xor(s1, off, 64);
        s2 += __shfl_xor(s2, off, 64);
    }
    __shared__ float l1[16], l2[16];
    const int wv = tid >> 6, lane = tid & 63;
    if (lane == 0) { l1[wv] = s1; l2[wv] = s2; }
    __syncthreads();
    float S1 = 0.f, S2 = 0.f;
    #pragma unroll
    for (int i = 0; i < 16; ++i) { S1 += l1[i]; S2 += l2[i]; }

    const float mu   = S1 * (1.0f / 512.0f);
    const float vr   = S2 * (1.0f / 512.0f) - mu * mu;
    const float rinv = rsqrtf(vr + LN_EPS);

    if (tid < 512) {
        const size_t o = (size_t)b * (KK * 512) + (size_t)k * 512;
        out[o + tid] = (val - mu) * rinv;
    }
}

// ---------------------------------------------------------------------------
extern "C" void kernel_launch(void* const* d_in, const int* in_sizes, int n_in,
                              void* d_out, int out_size, void* d_ws, size_t ws_size,
                              hipStream_t stream)
{
    const float* x       = (const float*)d_in[0];
    const float* centers = (const float*)d_in[1];
    const float* scale   = (const float*)d_in[2];
    const float* temp    = (const float*)d_in[3];
    float* out = (float*)d_out;

    // C=16: 256 blocks (1/CU) x 1024 threads; ws = 4.2 MB (was 16.8 MB @ C=64).
    int C = 16;
    while (C > 4 && ((size_t)BB * C * KK * 512 + (size_t)BB * C * KK) * 4 > ws_size)
        C >>= 1;
    const int NT = (TT / C) / (TILE * QUADS);   // tiles per quad

    float* ws_wx = (float*)d_ws;
    float* ws_w  = ws_wx + (size_t)BB * C * KK * 512;

    dim3 g1(C, BB);
    lde_fused3<<<g1, 1024, 0, stream>>>(x, centers, scale, temp, ws_wx, ws_w, C, NT);
    lde_final4<<<BB * KK, 1024, 0, stream>>>(ws_wx, ws_w, centers, out, C);
}